// Round 3
// baseline (3072.031 us; speedup 1.0000x reference)
//
#include <hip/hip_runtime.h>
#include <hip/hip_bf16.h>

// LSTMCellModel: only seq row 1023 feeds the output => batch-1 recurrence.
// Round 3: persistent cooperative kernel for the 256-cell-step serial chain.
//   - weights + A-slices LDS-resident per WG (staged once)
//   - custom two-level agent-scope grid barrier (8 group counters -> root -> gen)
//   - c-chain entirely in LDS; only the 1024-float h vector is exchanged globally
// ws layout (floats): A[128][2][4096] | Hh[128][1024] | hbuf[1024] | bar[352 u32]

#define IN_DIM 512
#define HDIM   1024
#define G4     4096
#define NSTEP  128
#define ODIM   1000
#define NWG    256

__device__ __forceinline__ float sigf(float x) { return 1.f / (1.f + __expf(-x)); }

// ---------------------------------------------------------------- k_prep
// A[t][cell][row] = sum_k w_ih[row,k] * 255*x[t,1023,k] + b_ih[row] + b_hh[row]
// grid 512 WGs x 256 thr. Block 0 additionally zeroes the barrier words.
__global__ void k_prep(const float* __restrict__ x,
                       const float* __restrict__ wih1, const float* __restrict__ bih1,
                       const float* __restrict__ bhh1,
                       const float* __restrict__ wih2, const float* __restrict__ bih2,
                       const float* __restrict__ bhh2,
                       float* __restrict__ A, unsigned* __restrict__ bar) {
    __shared__ float Wsh[16][IN_DIM + 1];
    __shared__ float xs[IN_DIM];
    const int tid = threadIdx.x;
    if (blockIdx.x == 0) {
        for (int i = tid; i < 352; i += 256) bar[i] = 0u;
    }
    const int R0   = blockIdx.x * 16;
    const int cell = R0 >> 12;
    const int row0 = R0 & 4095;
    const float* __restrict__ wih = cell ? wih2 : wih1;
    const float* __restrict__ bih = cell ? bih2 : bih1;
    const float* __restrict__ bhh = cell ? bhh2 : bhh1;

    for (int idx = tid; idx < 16 * (IN_DIM / 4); idx += 256) {
        int r  = idx / (IN_DIM / 4);
        int c4 = idx % (IN_DIM / 4);
        float4 v = ((const float4*)(wih + (size_t)(row0 + r) * IN_DIM))[c4];
        Wsh[r][c4 * 4 + 0] = v.x; Wsh[r][c4 * 4 + 1] = v.y;
        Wsh[r][c4 * 4 + 2] = v.z; Wsh[r][c4 * 4 + 3] = v.w;
    }
    const int row_local = tid >> 4;
    const int lane16    = tid & 15;
    const float bias = bih[row0 + row_local] + bhh[row0 + row_local];

    for (int t = 0; t < NSTEP; ++t) {
        __syncthreads();
        for (int idx = tid; idx < IN_DIM; idx += 256)
            xs[idx] = x[(size_t)t * HDIM * IN_DIM + (size_t)1023 * IN_DIM + idx] * 255.f;
        __syncthreads();
        float p = 0.f;
#pragma unroll
        for (int m = 0; m < 32; ++m)
            p += Wsh[row_local][lane16 + 16 * m] * xs[lane16 + 16 * m];
        p += __shfl_xor(p, 8); p += __shfl_xor(p, 4);
        p += __shfl_xor(p, 2); p += __shfl_xor(p, 1);
        if (lane16 == 0)
            A[((size_t)t * 2 + cell) * G4 + row0 + row_local] = p + bias;
    }
}

// ---------------------------------------------------------------- grid barrier
// Two-level: 8 group counters (32 arrivals each, 128B apart) -> root -> gen.
// Arrival fetch_add(ACQ_REL, agent) releases this WG's prior stores; waiters
// acquire on gen -> transitively synchronized with all producers.
__device__ __forceinline__ void gridbar(unsigned* __restrict__ bar,
                                        unsigned gen_target, int bid) {
    __syncthreads();  // drain this WG's h stores (vmcnt(0)) before arrival
    if (threadIdx.x == 0) {
        unsigned* cnt  = bar + ((bid >> 5) << 5);
        unsigned* root = bar + 256;
        unsigned* gen  = bar + 320;
        bool released = false;
        unsigned a = __hip_atomic_fetch_add(cnt, 1u, __ATOMIC_ACQ_REL,
                                            __HIP_MEMORY_SCOPE_AGENT);
        if (a == 31u) {
            unsigned r = __hip_atomic_fetch_add(root, 1u, __ATOMIC_ACQ_REL,
                                                __HIP_MEMORY_SCOPE_AGENT);
            if (r == 7u) {
                for (int i = 0; i < 8; ++i)
                    __hip_atomic_store(bar + (i << 5), 0u, __ATOMIC_RELAXED,
                                       __HIP_MEMORY_SCOPE_AGENT);
                __hip_atomic_store(root, 0u, __ATOMIC_RELAXED,
                                   __HIP_MEMORY_SCOPE_AGENT);
                __hip_atomic_store(gen, gen_target, __ATOMIC_RELEASE,
                                   __HIP_MEMORY_SCOPE_AGENT);
                released = true;
            }
        }
        if (!released) {
            int guard = 0;
            while (__hip_atomic_load(gen, __ATOMIC_RELAXED,
                                     __HIP_MEMORY_SCOPE_AGENT) != gen_target) {
                __builtin_amdgcn_s_sleep(1);
                if (++guard > (1 << 22)) break;  // deadlock bail (never in practice)
            }
            (void)__hip_atomic_load(gen, __ATOMIC_ACQUIRE,
                                    __HIP_MEMORY_SCOPE_AGENT);
        }
    }
    __syncthreads();
}

// ---------------------------------------------------------------- k_persist
// 256 WGs x 256 thr, 1 WG/CU (LDS-limited). WG b owns j0=4b.
// LDS: W1[16][1024] | W2[16][1024] | hs[1024] | As[256][16] | gs[16] | cs[4]
__global__ void __launch_bounds__(256, 1)
k_persist(const float* __restrict__ whh1, const float* __restrict__ whh2,
          const float* __restrict__ A, float* __restrict__ hbuf,
          float* __restrict__ Hh, unsigned* __restrict__ bar) {
    extern __shared__ float sm[];
    float* W1 = sm;                 // 16384
    float* W2 = W1 + 16 * 1024;     // 16384
    float* hs = W2 + 16 * 1024;     // 1024
    float* As = hs + 1024;          // 4096
    float* gs = As + 4096;          // 16
    float* cs = gs + 16;            // 4

    const int tid = threadIdx.x;
    const int bid = blockIdx.x;
    const int j0  = bid * 4;

    // ---- stage weights (32 rows x 4KB, coalesced float4) + A slice
    for (int idx = tid; idx < 16 * 256; idx += 256) {
        int lr = idx >> 8;              // local row 0..15
        int c4 = idx & 255;
        int q = lr >> 2, k = lr & 3;
        size_t gr = (size_t)(q * HDIM + j0 + k) * HDIM;
        ((float4*)(W1 + lr * HDIM))[c4] = ((const float4*)(whh1 + gr))[c4];
        ((float4*)(W2 + lr * HDIM))[c4] = ((const float4*)(whh2 + gr))[c4];
    }
    for (int idx = tid; idx < 4096; idx += 256) {
        int tc = idx >> 4;              // t*2+cell, 0..255
        int lr = idx & 15;
        int q = lr >> 2, k = lr & 3;
        As[tc * 16 + lr] = A[(size_t)tc * G4 + q * HDIM + j0 + k];
    }
    if (tid < 4) cs[tid] = 0.f;
    for (int i = tid; i < HDIM; i += 256) hs[i] = 0.f;
    __syncthreads();

    const int q = tid >> 6, lane = tid & 63;
    unsigned gen = 0;

    for (int t = 0; t < NSTEP; ++t) {
#pragma unroll
        for (int cell = 0; cell < 2; ++cell) {
            const float* W = cell ? W2 : W1;
            // gates: wave q computes rows q*H + j0+k, k=0..3
            float hv[16];
#pragma unroll
            for (int m = 0; m < 16; ++m) hv[m] = hs[lane + 64 * m];
            float p0 = 0.f, p1 = 0.f, p2 = 0.f, p3 = 0.f;
#pragma unroll
            for (int m = 0; m < 16; ++m) {
                const float h = hv[m];
                p0 += W[(q * 4 + 0) * HDIM + lane + 64 * m] * h;
                p1 += W[(q * 4 + 1) * HDIM + lane + 64 * m] * h;
                p2 += W[(q * 4 + 2) * HDIM + lane + 64 * m] * h;
                p3 += W[(q * 4 + 3) * HDIM + lane + 64 * m] * h;
            }
            float pr[4] = {p0, p1, p2, p3};
#pragma unroll
            for (int k = 0; k < 4; ++k) {
                float v = pr[k];
                v += __shfl_down(v, 32); v += __shfl_down(v, 16);
                v += __shfl_down(v, 8);  v += __shfl_down(v, 4);
                v += __shfl_down(v, 2);  v += __shfl_down(v, 1);
                if (lane == 0)
                    gs[q * 4 + k] = v + As[(t * 2 + cell) * 16 + q * 4 + k];
            }
            __syncthreads();
            float* hout = cell ? (Hh + (size_t)t * HDIM) : hbuf;
            if (tid < 4) {
                float iv = gs[tid], fv = gs[4 + tid], gv = gs[8 + tid],
                      ov = gs[12 + tid];
                float cn = sigf(fv) * cs[tid] + sigf(iv) * tanhf(gv);
                cs[tid] = cn;  // single c-chain threads through both cells
                hout[j0 + tid] = sigf(ov) * tanhf(cn);
            }
            gridbar(bar, ++gen, bid);
            // reload full h (4KB) into LDS
            ((float4*)hs)[tid] = ((const float4*)hout)[tid];
            __syncthreads();
        }
    }
}

// ---------------------------------------------------------------- k_fc
// out[t][o] = Hh[t] . wfc[o] + bfc[o]. grid 125 WGs x 256 thr.
__global__ void k_fc(const float* __restrict__ Hh, const float* __restrict__ wfc,
                     const float* __restrict__ bfc, float* __restrict__ out) {
    __shared__ float Wf[8][HDIM];
    const int tid = threadIdx.x;
    const int o0  = blockIdx.x * 8;
    for (int idx = tid; idx < 8 * (HDIM / 4); idx += 256) {
        int r  = idx >> 8;
        int c4 = idx & 255;
        float4 v = ((const float4*)(wfc + (size_t)(o0 + r) * HDIM))[c4];
        Wf[r][c4 * 4 + 0] = v.x; Wf[r][c4 * 4 + 1] = v.y;
        Wf[r][c4 * 4 + 2] = v.z; Wf[r][c4 * 4 + 3] = v.w;
    }
    __syncthreads();
    const int ol = tid >> 5, lane32 = tid & 31;
    const float bias = bfc[o0 + ol];
    for (int t = 0; t < NSTEP; ++t) {
        const float* __restrict__ hv = Hh + (size_t)t * HDIM;
        float p = 0.f;
#pragma unroll
        for (int m = 0; m < 32; ++m)
            p += hv[lane32 + 32 * m] * Wf[ol][lane32 + 32 * m];
        p += __shfl_xor(p, 16); p += __shfl_xor(p, 8); p += __shfl_xor(p, 4);
        p += __shfl_xor(p, 2);  p += __shfl_xor(p, 1);
        if (lane32 == 0)
            out[t * ODIM + o0 + ol] = p + bias;
    }
}

// ---------------------------------------------------------------- launch
extern "C" void kernel_launch(void* const* d_in, const int* in_sizes, int n_in,
                              void* d_out, int out_size, void* d_ws, size_t ws_size,
                              hipStream_t stream) {
    const float* x    = (const float*)d_in[0];
    const float* wih1 = (const float*)d_in[1];
    const float* whh1 = (const float*)d_in[2];
    const float* bih1 = (const float*)d_in[3];
    const float* bhh1 = (const float*)d_in[4];
    const float* wih2 = (const float*)d_in[5];
    const float* whh2 = (const float*)d_in[6];
    const float* bih2 = (const float*)d_in[7];
    const float* bhh2 = (const float*)d_in[8];
    const float* wfc  = (const float*)d_in[9];
    const float* bfc  = (const float*)d_in[10];
    float* out = (float*)d_out;

    float*    A    = (float*)d_ws;                    // 128*2*4096
    float*    Hh   = A + (size_t)NSTEP * 2 * G4;      // 128*1024
    float*    hbuf = Hh + (size_t)NSTEP * HDIM;       // 1024
    unsigned* bar  = (unsigned*)(hbuf + HDIM);        // 352 u32

    hipLaunchKernelGGL(k_prep, dim3(512), dim3(256), 0, stream,
                       x, wih1, bih1, bhh1, wih2, bih2, bhh2, A, bar);

    const size_t smem = (size_t)(16384 + 16384 + 1024 + 4096 + 16 + 4) * 4;
    static bool attr_set = false;   // idempotent config, not stream work
    hipFuncSetAttribute((const void*)k_persist,
                        hipFuncAttributeMaxDynamicSharedMemorySize, (int)smem);
    (void)attr_set;

    void* args[6];
    args[0] = (void*)&whh1; args[1] = (void*)&whh2; args[2] = (void*)&A;
    args[3] = (void*)&hbuf; args[4] = (void*)&Hh;   args[5] = (void*)&bar;
    hipLaunchCooperativeKernel((void*)k_persist, dim3(NWG), dim3(256),
                               args, (unsigned)smem, stream);

    hipLaunchKernelGGL(k_fc, dim3(125), dim3(256), 0, stream, Hh, wfc, bfc, out);
}